// Round 10
// baseline (307.807 us; speedup 1.0000x reference)
//
#include <hip/hip_runtime.h>
#include <hip/hip_fp16.h>

#define NN 100000
#define NE 1250000
#define NBIN 512
#define RBIN 196          // ceil(NN/NBIN); bin b covers nodes [b*196, b*196+196)
#define PAD 16            // counter padding: 16 ints = 64B line
#define CAP 4096          // binD LDS edge-staging capacity (int2 = 32KB)
#define EPB 4096          // binC edges per block
#define EPT 16            // EPB/256
#define BCAP 3072         // fixed per-bin capacity (mean 2441 + 13 sigma)
// src chunking: chunk = src >> 15 (4 windows of 32768 nodes = 4.19MB of P each)

__device__ __forceinline__ int eidx(const int* __restrict__ e32, int f, int i){
    return f ? e32[2*(size_t)i] : e32[i];
}

// one-wave exclusive scan of the 512 global bin counters into LDS boff[]
__device__ __forceinline__ void scan_bins(const int* __restrict__ cnts, int* __restrict__ boff){
    if(threadIdx.x < 64){
        int b0 = threadIdx.x*8;
        int pre[8]; int run = 0;
        #pragma unroll
        for(int i = 0; i < 8; ++i){ pre[i] = run; run += cnts[(b0+i)*PAD]; }
        int inc = run;
        for(int o = 1; o < 64; o <<= 1){
            int u = __shfl_up(inc, o, 64);
            if(threadIdx.x >= (unsigned)o) inc += u;
        }
        int excl = inc - run;
        #pragma unroll
        for(int i = 0; i < 8; ++i) boff[b0+i] = excl + pre[i];
    }
    __syncthreads();
}

// ---------------- pass C: block multi-split scatter into fixed-capacity dst-bins ----------------
__global__ __launch_bounds__(256) void binC_k(const int* __restrict__ e32,
                                              int* __restrict__ binCur, int2* __restrict__ bins){
    __shared__ int2 ST[EPB];          // 32KB staged edges, grouped by bin
    __shared__ int hist[NBIN];
    __shared__ int lstart[NBIN];
    __shared__ int gbase[NBIN];
    __shared__ int cur[NBIN];
    __shared__ int flg;
    const int t = threadIdx.x;
    const int e0 = blockIdx.x * EPB;
    const int n = min(EPB, NE - e0);

    for(int b = t; b < NBIN; b += 256){ hist[b] = 0; cur[b] = 0; }
    if(t < 64){
        int v = e32[2*t + 1];
        unsigned long long b = __ballot(v != 0);
        if(t == 0) flg = (b == 0ULL) ? 1 : 0;
    }
    __syncthreads();
    const int f = flg;

    int2 ed[EPT];
    #pragma unroll
    for(int k = 0; k < EPT; ++k){
        int i = k*256 + t;
        if(i < n){
            ed[k].x = eidx(e32, f, e0 + i);
            ed[k].y = eidx(e32, f, NE + e0 + i);
            atomicAdd(&hist[ed[k].y / RBIN], 1);
        }
    }
    __syncthreads();

    if(t < 64){
        int b0 = t*8;
        int pre[8]; int run = 0;
        #pragma unroll
        for(int i = 0; i < 8; ++i){ pre[i] = run; run += hist[b0 + i]; }
        int inc = run;
        for(int o = 1; o < 64; o <<= 1){
            int u = __shfl_up(inc, o, 64);
            if(t >= o) inc += u;
        }
        int excl = inc - run;
        #pragma unroll
        for(int i = 0; i < 8; ++i) lstart[b0 + i] = excl + pre[i];
    }
    for(int b = t; b < NBIN; b += 256) gbase[b] = b*BCAP + atomicAdd(&binCur[b*PAD], hist[b]);
    __syncthreads();

    #pragma unroll
    for(int k = 0; k < EPT; ++k){
        int i = k*256 + t;
        if(i < n){
            int b = ed[k].y / RBIN;
            int lo = atomicAdd(&cur[b], 1);
            ST[lstart[b] + lo] = ed[k];
        }
    }
    __syncthreads();

    for(int i = t; i < n; i += 256){
        int2 e = ST[i];
        int b = e.y / RBIN;
        bins[gbase[b] + (i - lstart[b])] = e;
    }
}

// ---------------- pass D: per-bin CSR build sorted by (dst, src-chunk) -> rp, rp4, dinv, csr_src ----------------
__global__ __launch_bounds__(256) void binD_k(const int2* __restrict__ bins, const int* __restrict__ binCur,
                                              int* __restrict__ rp, int* __restrict__ rp4,
                                              float* __restrict__ dinv, int* __restrict__ csr_src){
    __shared__ int2 ES[CAP];          // 32 KB
    __shared__ int hist[1024];
    __shared__ int scx[1024];
    __shared__ int cur[1024];
    __shared__ int red[256];
    __shared__ int boff[NBIN];
    const int b = blockIdx.x;
    const int t = threadIdx.x;
    if(b == NBIN-1 && t == 0) rp[NN] = NE;
    const int nbase = b * RBIN;
    if(nbase >= NN) return;                      // empty trailing bin
    const int nend = min(nbase + RBIN, NN);
    const int nr = nend - nbase;
    for(int i = t; i < 1024; i += 256){ hist[i] = 0; cur[i] = 0; }
    __syncthreads();
    scan_bins(binCur, boff);                     // compact global offsets from final counts
    const int off0 = boff[b];
    const int rb   = b * BCAP;
    const int cnt  = binCur[b*PAD];

    const bool single = (cnt <= CAP);
    // histogram phase: key = local_dst*4 + src_chunk
    for(int c0 = 0; c0 < cnt; c0 += CAP){
        int n = min(CAP, cnt - c0);
        for(int i = t; i < n; i += 256) ES[i] = bins[rb + c0 + i];
        __syncthreads();
        for(int i = t; i < n; i += 256)
            atomicAdd(&hist[(ES[i].y - nbase)*4 + (ES[i].x >> 15)], 1);
        __syncthreads();
    }
    // scan 1024 keys: thread t owns keys 4t..4t+3 (== node nbase+t's 4 chunks)
    int h0 = hist[t*4], h1 = hist[t*4+1], h2 = hist[t*4+2], h3 = hist[t*4+3];
    int run = h0 + h1 + h2 + h3;
    red[t] = run; __syncthreads();
    for(int off = 1; off < 256; off <<= 1){
        int u = (t >= off) ? red[t - off] : 0;
        __syncthreads();
        red[t] += u;
        __syncthreads();
    }
    int ebase = red[t] - run;                    // exclusive over nodes
    scx[t*4]   = ebase;
    scx[t*4+1] = ebase + h0;
    scx[t*4+2] = ebase + h0 + h1;
    scx[t*4+3] = ebase + h0 + h1 + h2;
    if(t < nr){
        rp[nbase + t] = off0 + ebase;
        int4 w = make_int4(off0 + ebase, off0 + ebase + h0,
                           off0 + ebase + h0 + h1, off0 + ebase + h0 + h1 + h2);
        *(int4*)&rp4[(size_t)(nbase + t)*4] = w;
        dinv[nbase + t] = rsqrtf((float)(run + 1));   // +1 = self loop
    }
    __syncthreads();
    // scatter phase
    for(int c0 = 0; c0 < cnt; c0 += CAP){
        int n = min(CAP, cnt - c0);
        if(!single){
            for(int i = t; i < n; i += 256) ES[i] = bins[rb + c0 + i];
            __syncthreads();
        }
        for(int i = t; i < n; i += 256){
            int k = (ES[i].y - nbase)*4 + (ES[i].x >> 15);
            int p = atomicAdd(&cur[k], 1);
            csr_src[off0 + scx[k] + p] = ES[i].x;
        }
        if(!single) __syncthreads();
    }
}

// ---------------- dense GEMM, K-tiled: out[row] = fp16( (A@W)[row] * dinv[row] ) ----------------
template<bool AHALF, int K, int NC, int KT, int OSTR, bool RELU>
__global__ __launch_bounds__(256) void gemm_k(const void* __restrict__ Araw, const float* __restrict__ W,
                                              const float* __restrict__ dinv,
                                              __half* __restrict__ out, int M){
    constexpr int CHT = KT/4;
    constexpr int CMASK = CHT - 1;
    __shared__ float Xs[64*KT];
    __shared__ float Ws[KT*NC];
    const int tid  = threadIdx.x;
    const int base = blockIdx.x * 64;
    const int tx = tid & 15, ty = tid >> 4;
    const int c0 = tx * 4;
    float acc[4][4] = {};

    for(int k0 = 0; k0 < K; k0 += KT){
        {
            const float4* Wv = (const float4*)(W + k0*NC);
            float4* Wsv = (float4*)Ws;
            for(int i = tid; i < KT*NC/4; i += 256) Wsv[i] = Wv[i];
        }
        {
            const int ch = tid & (CHT - 1);
            const int r0 = tid / CHT;
            constexpr int RSTEP = 256 / CHT;
            #pragma unroll
            for(int r = r0; r < 64; r += RSTEP){
                int row = base + r; if(row >= M) row = M - 1;
                float4 v;
                if(AHALF){
                    const __half2* ap = (const __half2*)((const __half*)Araw + (size_t)row*K + k0 + ch*4);
                    float2 fa = __half22float2(ap[0]), fb = __half22float2(ap[1]);
                    v = make_float4(fa.x, fa.y, fb.x, fb.y);
                } else {
                    v = *(const float4*)((const float*)Araw + (size_t)row*K + k0 + ch*4);
                }
                if(RELU){ v.x=fmaxf(v.x,0.f); v.y=fmaxf(v.y,0.f); v.z=fmaxf(v.z,0.f); v.w=fmaxf(v.w,0.f); }
                int sw = (ch + r) & CMASK;
                *(float4*)&Xs[r*KT + sw*4] = v;
            }
        }
        __syncthreads();

        if(c0 < NC){
            for(int k4 = 0; k4 < CHT; ++k4){
                float4 xs[4];
                #pragma unroll
                for(int i = 0; i < 4; ++i){
                    int r = ty*4 + i;
                    int sw = (k4 + r) & CMASK;
                    xs[i] = *(const float4*)&Xs[r*KT + (sw << 2)];
                }
                float4 wsv[4];
                #pragma unroll
                for(int kk = 0; kk < 4; ++kk) wsv[kk] = *(const float4*)&Ws[(k4*4 + kk)*NC + c0];
                #pragma unroll
                for(int kk = 0; kk < 4; ++kk){
                    const float* wp = (const float*)&wsv[kk];
                    #pragma unroll
                    for(int i = 0; i < 4; ++i){
                        float xv = ((const float*)&xs[i])[kk];
                        #pragma unroll
                        for(int j = 0; j < 4; ++j) acc[i][j] += xv * wp[j];
                    }
                }
            }
        }
        __syncthreads();
    }
    #pragma unroll
    for(int i = 0; i < 4; ++i){
        int row = base + ty*4 + i;
        if(row < M && c0 < NC){
            float dv = dinv[row];
            __half2 h01 = __floats2half2_rn(acc[i][0]*dv, acc[i][1]*dv);
            __half2 h23 = __floats2half2_rn(acc[i][2]*dv, acc[i][3]*dv);
            __half2* dst = (__half2*)&out[(size_t)row*OSTR + c0];
            dst[0] = h01;
            dst[1] = h23;
        }
    }
}

// ---------------- shared gather body (F=64): 16 lanes/edge, 4 edges/wave-instr ----------------
__device__ __forceinline__ void gather64(const __half2* __restrict__ P2, const int* __restrict__ csr_src,
                                         int j, int end, int g, unsigned qo, float4& acc){
    constexpr unsigned F2 = 32;
    #pragma unroll 1
    for(; j + 16 <= end; j += 16){
        unsigned i0 = (unsigned)csr_src[j + g]     *F2 + qo;
        unsigned i1 = (unsigned)csr_src[j + 4 + g] *F2 + qo;
        unsigned i2 = (unsigned)csr_src[j + 8 + g] *F2 + qo;
        unsigned i3 = (unsigned)csr_src[j + 12 + g]*F2 + qo;
        __half2 a0 = P2[i0], b0 = P2[i0+1];
        __half2 a1 = P2[i1], b1 = P2[i1+1];
        __half2 a2 = P2[i2], b2 = P2[i2+1];
        __half2 a3 = P2[i3], b3 = P2[i3+1];
        __half2 sa = __hadd2(a0, a1), sb = __hadd2(b0, b1);
        __half2 ta = __hadd2(a2, a3), tb = __hadd2(b2, b3);
        float2 f0 = __half22float2(sa), f1 = __half22float2(sb);
        float2 f2 = __half22float2(ta), f3 = __half22float2(tb);
        acc.x += f0.x + f2.x; acc.y += f0.y + f2.y;
        acc.z += f1.x + f3.x; acc.w += f1.y + f3.y;
    }
    if(j + 8 <= end){
        unsigned i0 = (unsigned)csr_src[j + g]    *F2 + qo;
        unsigned i1 = (unsigned)csr_src[j + 4 + g]*F2 + qo;
        __half2 a0 = P2[i0], b0 = P2[i0+1];
        __half2 a1 = P2[i1], b1 = P2[i1+1];
        __half2 sa = __hadd2(a0, a1), sb = __hadd2(b0, b1);
        float2 f0 = __half22float2(sa), f1 = __half22float2(sb);
        acc.x += f0.x; acc.y += f0.y; acc.z += f1.x; acc.w += f1.y;
        j += 8;
    }
    if(j + 4 <= end){
        unsigned i0 = (unsigned)csr_src[j + g]*F2 + qo;
        __half2 a = P2[i0], b = P2[i0+1];
        float2 fa = __half22float2(a), fb = __half22float2(b);
        acc.x += fa.x; acc.y += fa.y; acc.z += fb.x; acc.w += fb.y;
        j += 4;
    }
    const int rem = end - j;
    if(g < rem){
        unsigned i0 = (unsigned)csr_src[j + g]*F2 + qo;
        __half2 a = P2[i0], b = P2[i0+1];
        float2 fa = __half22float2(a), fb = __half22float2(b);
        acc.x += fa.x; acc.y += fa.y; acc.z += fb.x; acc.w += fb.y;
    }
}

// ---------------- single-pass CSR aggregation F=64 -> fp16 G ----------------
__global__ __launch_bounds__(256) void agg64_k(const __half* __restrict__ P, const int* __restrict__ rp,
                                               const int* __restrict__ csr_src,
                                               const float* __restrict__ dinv, const float* __restrict__ bias,
                                               __half* __restrict__ G){
    constexpr unsigned F2 = 32;
    const int lane = threadIdx.x & 63;
    const int v = (blockIdx.x*256 + threadIdx.x) >> 6;
    if(v >= NN) return;
    const int g = lane >> 4;
    const int q = lane & 15;
    const unsigned qo = (unsigned)q*2;
    const __half2* __restrict__ P2 = (const __half2*)P;

    const int beg = rp[v], end = rp[v + 1];
    float4 acc = make_float4(0.f, 0.f, 0.f, 0.f);
    if(g == 0){                                   // self-loop term
        __half2 a = P2[(unsigned)v*F2 + qo], b = P2[(unsigned)v*F2 + qo + 1];
        float2 fa = __half22float2(a), fb = __half22float2(b);
        acc = make_float4(fa.x, fa.y, fb.x, fb.y);
    }
    gather64(P2, csr_src, beg, end, g, qo, acc);

    #pragma unroll
    for(int m = 16; m <= 32; m <<= 1){
        acc.x += __shfl_xor(acc.x, m, 64);
        acc.y += __shfl_xor(acc.y, m, 64);
        acc.z += __shfl_xor(acc.z, m, 64);
        acc.w += __shfl_xor(acc.w, m, 64);
    }

    if(g == 0){
        const float d = dinv[v];
        float4 bb = *(const float4*)&bias[q*4];
        __half2 h01 = __floats2half2_rn(fmaf(acc.x, d, bb.x), fmaf(acc.y, d, bb.y));
        __half2 h23 = __floats2half2_rn(fmaf(acc.z, d, bb.z), fmaf(acc.w, d, bb.w));
        __half2* dst = (__half2*)&G[(size_t)v*64 + q*4];
        dst[0] = h01;
        dst[1] = h23;
    }
}

// ---------------- src-chunked CSR aggregation F=64, pass C of 4 (A/B experiment, layer 1) ----------------
// Pass c gathers only edges with src in [c*32768,(c+1)*32768) -> L2-window locality.
// fp16 partial accumulation in Gpart; last pass adds self-term + epilogue -> G.
template<int C>
__global__ __launch_bounds__(256) void agg64c_k(const __half* __restrict__ P, const int* __restrict__ rp,
                                                const int* __restrict__ rp4, const int* __restrict__ csr_src,
                                                const float* __restrict__ dinv, const float* __restrict__ bias,
                                                __half* __restrict__ Gpart, __half* __restrict__ G){
    constexpr bool FIRST = (C == 0), LAST = (C == 3);
    constexpr unsigned F2 = 32;
    const int lane = threadIdx.x & 63;
    const int v = (blockIdx.x*256 + threadIdx.x) >> 6;
    if(v >= NN) return;
    const int g = lane >> 4;
    const int q = lane & 15;
    const unsigned qo = (unsigned)q*2;
    const __half2* __restrict__ P2 = (const __half2*)P;

    int4 s4 = *(const int4*)&rp4[(size_t)v*4];
    int beg = (C == 0) ? s4.x : (C == 1) ? s4.y : (C == 2) ? s4.z : s4.w;
    int end;
    if(LAST) end = rp[v + 1];
    else     end = (C == 0) ? s4.y : (C == 1) ? s4.z : s4.w;

    float4 acc = make_float4(0.f, 0.f, 0.f, 0.f);
    if(LAST && g == 0){                           // self-loop term (streaming, last pass)
        __half2 a = P2[(unsigned)v*F2 + qo], b = P2[(unsigned)v*F2 + qo + 1];
        float2 fa = __half22float2(a), fb = __half22float2(b);
        acc = make_float4(fa.x, fa.y, fb.x, fb.y);
    }
    gather64(P2, csr_src, beg, end, g, qo, acc);

    #pragma unroll
    for(int m = 16; m <= 32; m <<= 1){
        acc.x += __shfl_xor(acc.x, m, 64);
        acc.y += __shfl_xor(acc.y, m, 64);
        acc.z += __shfl_xor(acc.z, m, 64);
        acc.w += __shfl_xor(acc.w, m, 64);
    }

    if(g == 0){
        __half2* gp = (__half2*)&Gpart[(size_t)v*64 + q*4];
        if(!FIRST){
            float2 p0 = __half22float2(gp[0]), p1 = __half22float2(gp[1]);
            acc.x += p0.x; acc.y += p0.y; acc.z += p1.x; acc.w += p1.y;
        }
        if(!LAST){
            gp[0] = __floats2half2_rn(acc.x, acc.y);
            gp[1] = __floats2half2_rn(acc.z, acc.w);
        } else {
            const float d = dinv[v];
            float4 bb = *(const float4*)&bias[q*4];
            __half2 h01 = __floats2half2_rn(fmaf(acc.x, d, bb.x), fmaf(acc.y, d, bb.y));
            __half2 h23 = __floats2half2_rn(fmaf(acc.z, d, bb.z), fmaf(acc.w, d, bb.w));
            __half2* dst = (__half2*)&G[(size_t)v*64 + q*4];
            dst[0] = h01;
            dst[1] = h23;
        }
    }
}

// ---------------- final CSR aggregation (F=40, padded stride 64) + fused log_softmax ----------------
__global__ __launch_bounds__(256) void agg40_k(const __half* __restrict__ P, const int* __restrict__ rp,
                                               const int* __restrict__ csr_src,
                                               const float* __restrict__ dinv, const float* __restrict__ bias,
                                               float* __restrict__ G){
    constexpr int NQ = 10;
    constexpr unsigned F2 = 32;                   // padded half2 stride (128B rows)
    const int lane = threadIdx.x & 63;
    const int v = (blockIdx.x*256 + threadIdx.x) >> 6;
    if(v >= NN) return;
    const int g = lane >> 4;
    const int q = lane & 15;
    const bool qa = (q < NQ);
    const unsigned qo = (unsigned)q*2;
    const __half2* __restrict__ P2 = (const __half2*)P;

    const int beg = rp[v], end = rp[v + 1];
    float4 acc = make_float4(0.f, 0.f, 0.f, 0.f);
    if(g == 0 && qa){
        __half2 a = P2[(unsigned)v*F2 + qo], b = P2[(unsigned)v*F2 + qo + 1];
        float2 fa = __half22float2(a), fb = __half22float2(b);
        acc = make_float4(fa.x, fa.y, fb.x, fb.y);
    }

    int j = beg;
    #pragma unroll 1
    for(; j + 8 <= end; j += 8){
        unsigned i0 = (unsigned)csr_src[j + g]    *F2 + qo;
        unsigned i1 = (unsigned)csr_src[j + 4 + g]*F2 + qo;
        __half2 a0 = P2[i0], b0 = P2[i0+1];
        __half2 a1 = P2[i1], b1 = P2[i1+1];
        __half2 sa = __hadd2(a0, a1), sb = __hadd2(b0, b1);
        float2 f0 = __half22float2(sa), f1 = __half22float2(sb);
        acc.x += f0.x; acc.y += f0.y; acc.z += f1.x; acc.w += f1.y;
    }
    if(j + 4 <= end){
        unsigned i0 = (unsigned)csr_src[j + g]*F2 + qo;
        __half2 a = P2[i0], b = P2[i0+1];
        float2 fa = __half22float2(a), fb = __half22float2(b);
        acc.x += fa.x; acc.y += fa.y; acc.z += fb.x; acc.w += fb.y;
        j += 4;
    }
    const int rem = end - j;
    if(g < rem){
        unsigned i0 = (unsigned)csr_src[j + g]*F2 + qo;
        __half2 a = P2[i0], b = P2[i0+1];
        float2 fa = __half22float2(a), fb = __half22float2(b);
        acc.x += fa.x; acc.y += fa.y; acc.z += fb.x; acc.w += fb.y;
    }

    #pragma unroll
    for(int m = 16; m <= 32; m <<= 1){
        acc.x += __shfl_xor(acc.x, m, 64);
        acc.y += __shfl_xor(acc.y, m, 64);
        acc.z += __shfl_xor(acc.z, m, 64);
        acc.w += __shfl_xor(acc.w, m, 64);
    }

    float4 r;
    const float d = dinv[v];
    if(g == 0 && qa){
        float4 bb = *(const float4*)&bias[q*4];
        r.x = fmaf(acc.x, d, bb.x);
        r.y = fmaf(acc.y, d, bb.y);
        r.z = fmaf(acc.z, d, bb.z);
        r.w = fmaf(acc.w, d, bb.w);
    }
    float lm = (g == 0 && qa) ? fmaxf(fmaxf(r.x, r.y), fmaxf(r.z, r.w)) : -3.402823466e38f;
    #pragma unroll
    for(int m = 1; m <= 8; m <<= 1) lm = fmaxf(lm, __shfl_xor(lm, m, 64));
    float ls = (g == 0 && qa)
             ? (__expf(r.x - lm) + __expf(r.y - lm) + __expf(r.z - lm) + __expf(r.w - lm)) : 0.0f;
    #pragma unroll
    for(int m = 1; m <= 8; m <<= 1) ls += __shfl_xor(ls, m, 64);
    if(g == 0 && qa){
        float lz = lm + __logf(ls);
        r.x -= lz; r.y -= lz; r.z -= lz; r.w -= lz;
        *(float4*)&G[(size_t)v*40 + q*4] = r;
    }
}

extern "C" void kernel_launch(void* const* d_in, const int* in_sizes, int n_in,
                              void* d_out, int out_size, void* d_ws, size_t ws_size,
                              hipStream_t stream){
    const float* x   = (const float*)d_in[0];
    const int*   e32 = (const int*)  d_in[1];
    const float* W1  = (const float*)d_in[2];
    const float* b1  = (const float*)d_in[3];
    const float* W2  = (const float*)d_in[4];
    const float* b2  = (const float*)d_in[5];
    const float* W3  = (const float*)d_in[6];
    const float* b3  = (const float*)d_in[7];
    float* out = (float*)d_out;

    char* ws = (char*)d_ws;
    size_t off = 0;
    auto alloc = [&](size_t bytes) -> void* {
        void* p = ws + off;
        off = (off + bytes + 255) & ~(size_t)255;
        return p;
    };
    int*    binCur = (int*)   alloc((size_t)NBIN*PAD*4);   // 32KB, zeroed
    int*    rp     = (int*)   alloc((size_t)(NN+1)*4);
    int*    rp4    = (int*)   alloc((size_t)NN*4*4);       // per-(node,chunk) segment starts
    float*  dinv   = (float*) alloc((size_t)NN*4);
    int*    csr_s  = (int*)   alloc((size_t)NE*4);
    __half* ph     = (__half*)alloc((size_t)NN*64*2);   // fp16 message matrix P (stride 64 all layers)
    __half* gA     = (__half*)alloc((size_t)NN*64*2);   // fp16 intermediate G
    __half* gB     = (__half*)alloc((size_t)NN*64*2);   // doubles as layer-1 Gpart scratch
    int2*   bins   = (int2*)  alloc((size_t)NBIN*BCAP*8); // 12.6MB fixed-capacity bins

    hipMemsetAsync(binCur, 0, (size_t)NBIN*PAD*4, stream);
    binC_k<<<(NE + EPB - 1)/EPB, 256, 0, stream>>>(e32, binCur, bins);
    binD_k<<<NBIN, 256, 0, stream>>>(bins, binCur, rp, rp4, dinv, csr_s);

    const int GEMM_GRID = (NN + 63)/64;        // 1563
    const int AGG_GRID  = (NN*64 + 255)/256;   // 25000

    gemm_k<false,128,64,64,64,false><<<GEMM_GRID, 256, 0, stream>>>(x,  W1, dinv, ph, NN);
    // layer 1: src-chunked 4-pass aggregation (A/B experiment vs layer 2's single pass)
    agg64c_k<0><<<AGG_GRID, 256, 0, stream>>>(ph, rp, rp4, csr_s, dinv, b1, gB, gA);
    agg64c_k<1><<<AGG_GRID, 256, 0, stream>>>(ph, rp, rp4, csr_s, dinv, b1, gB, gA);
    agg64c_k<2><<<AGG_GRID, 256, 0, stream>>>(ph, rp, rp4, csr_s, dinv, b1, gB, gA);
    agg64c_k<3><<<AGG_GRID, 256, 0, stream>>>(ph, rp, rp4, csr_s, dinv, b1, gB, gA);
    gemm_k<true, 64,64,64,64,true ><<<GEMM_GRID, 256, 0, stream>>>(gA, W2, dinv, ph, NN);
    // layer 2: single-pass control
    agg64_k<<<AGG_GRID, 256, 0, stream>>>(ph, rp, csr_s, dinv, b2, gB);
    gemm_k<true, 64,40,64,64,true ><<<GEMM_GRID, 256, 0, stream>>>(gB, W3, dinv, ph, NN);
    agg40_k<<<AGG_GRID, 256, 0, stream>>>(ph, rp, csr_s, dinv, b3, out);
}

// Round 11
// 245.327 us; speedup vs baseline: 1.2547x; 1.2547x over previous
//
#include <hip/hip_runtime.h>
#include <hip/hip_fp16.h>

#define NN 100000
#define NE 1250000
#define NBIN 512
#define RBIN 196          // ceil(NN/NBIN); bin b covers nodes [b*196, b*196+196)
#define PAD 16            // counter padding: 16 ints = 64B line
#define CAP 4096          // binD LDS edge-staging capacity (int2 = 32KB)
#define EPB 4096          // binC edges per block
#define EPT 16            // EPB/256
#define BCAP 3072         // fixed per-bin capacity (mean 2441 + 13 sigma)

__device__ __forceinline__ int eidx(const int* __restrict__ e32, int f, int i){
    return f ? e32[2*(size_t)i] : e32[i];
}

// one-wave exclusive scan of the 512 global bin counters into LDS boff[]
__device__ __forceinline__ void scan_bins(const int* __restrict__ cnts, int* __restrict__ boff){
    if(threadIdx.x < 64){
        int b0 = threadIdx.x*8;
        int pre[8]; int run = 0;
        #pragma unroll
        for(int i = 0; i < 8; ++i){ pre[i] = run; run += cnts[(b0+i)*PAD]; }
        int inc = run;
        for(int o = 1; o < 64; o <<= 1){
            int u = __shfl_up(inc, o, 64);
            if(threadIdx.x >= (unsigned)o) inc += u;
        }
        int excl = inc - run;
        #pragma unroll
        for(int i = 0; i < 8; ++i) boff[b0+i] = excl + pre[i];
    }
    __syncthreads();
}

// ---------------- pass C: block multi-split scatter into fixed-capacity dst-bins ----------------
__global__ __launch_bounds__(256) void binC_k(const int* __restrict__ e32,
                                              int* __restrict__ binCur, int2* __restrict__ bins){
    __shared__ int2 ST[EPB];          // 32KB staged edges, grouped by bin
    __shared__ int hist[NBIN];
    __shared__ int lstart[NBIN];
    __shared__ int gbase[NBIN];
    __shared__ int cur[NBIN];
    __shared__ int flg;
    const int t = threadIdx.x;
    const int e0 = blockIdx.x * EPB;
    const int n = min(EPB, NE - e0);

    for(int b = t; b < NBIN; b += 256){ hist[b] = 0; cur[b] = 0; }
    if(t < 64){
        int v = e32[2*t + 1];
        unsigned long long b = __ballot(v != 0);
        if(t == 0) flg = (b == 0ULL) ? 1 : 0;
    }
    __syncthreads();
    const int f = flg;

    // load edges to registers + LDS histogram
    int2 ed[EPT];
    #pragma unroll
    for(int k = 0; k < EPT; ++k){
        int i = k*256 + t;
        if(i < n){
            ed[k].x = eidx(e32, f, e0 + i);
            ed[k].y = eidx(e32, f, NE + e0 + i);
            atomicAdd(&hist[ed[k].y / RBIN], 1);
        }
    }
    __syncthreads();

    // single-wave exclusive scan of block-local hist
    if(t < 64){
        int b0 = t*8;
        int pre[8]; int run = 0;
        #pragma unroll
        for(int i = 0; i < 8; ++i){ pre[i] = run; run += hist[b0 + i]; }
        int inc = run;
        for(int o = 1; o < 64; o <<= 1){
            int u = __shfl_up(inc, o, 64);
            if(t >= o) inc += u;
        }
        int excl = inc - run;
        #pragma unroll
        for(int i = 0; i < 8; ++i) lstart[b0 + i] = excl + pre[i];
    }
    // reserve contiguous ranges at fixed per-bin bases (one atomic per bin per block)
    for(int b = t; b < NBIN; b += 256) gbase[b] = b*BCAP + atomicAdd(&binCur[b*PAD], hist[b]);
    __syncthreads();

    // scatter into LDS grouped by bin
    #pragma unroll
    for(int k = 0; k < EPT; ++k){
        int i = k*256 + t;
        if(i < n){
            int b = ed[k].y / RBIN;
            int lo = atomicAdd(&cur[b], 1);
            ST[lstart[b] + lo] = ed[k];
        }
    }
    __syncthreads();

    // linear copy-out: consecutive staged entries in a bin -> consecutive global slots
    for(int i = t; i < n; i += 256){
        int2 e = ST[i];
        int b = e.y / RBIN;
        bins[gbase[b] + (i - lstart[b])] = e;
    }
}

// ---------------- pass D: per-bin CSR build (rp, dinv, csr_src), inline scan of counts ----------------
__global__ __launch_bounds__(256) void binD_k(const int2* __restrict__ bins, const int* __restrict__ binCur,
                                              int* __restrict__ rp, float* __restrict__ dinv,
                                              int* __restrict__ csr_src){
    __shared__ int2 ES[CAP];
    __shared__ int hist[256];
    __shared__ int sc[256];
    __shared__ int cur[256];
    __shared__ int boff[NBIN];
    const int b = blockIdx.x;
    const int t = threadIdx.x;
    if(b == NBIN-1 && t == 0) rp[NN] = NE;
    const int nbase = b * RBIN;
    if(nbase >= NN) return;                      // empty trailing bin
    const int nend = min(nbase + RBIN, NN);
    const int nr = nend - nbase;
    hist[t] = 0; cur[t] = 0;
    __syncthreads();
    scan_bins(binCur, boff);                     // compact global offsets from final counts
    const int off0 = boff[b];                    // compact csr offset
    const int rb   = b * BCAP;                   // bins read base
    const int cnt  = binCur[b*PAD];

    const bool single = (cnt <= CAP);
    // histogram phase
    for(int c0 = 0; c0 < cnt; c0 += CAP){
        int n = min(CAP, cnt - c0);
        for(int i = t; i < n; i += 256) ES[i] = bins[rb + c0 + i];
        __syncthreads();
        for(int i = t; i < n; i += 256) atomicAdd(&hist[ES[i].y - nbase], 1);
        __syncthreads();
    }
    // exclusive scan of hist into sc
    int v = hist[t];
    sc[t] = v; __syncthreads();
    for(int off = 1; off < 256; off <<= 1){
        int u = (t >= off) ? sc[t - off] : 0;
        __syncthreads();
        sc[t] += u;
        __syncthreads();
    }
    int excl = sc[t] - v;
    sc[t] = excl;
    if(t < nr){
        rp[nbase + t]   = off0 + excl;
        dinv[nbase + t] = rsqrtf((float)(v + 1));   // +1 = self loop
    }
    __syncthreads();
    // scatter phase (ES still valid if single chunk)
    for(int c0 = 0; c0 < cnt; c0 += CAP){
        int n = min(CAP, cnt - c0);
        if(!single){
            for(int i = t; i < n; i += 256) ES[i] = bins[rb + c0 + i];
            __syncthreads();
        }
        for(int i = t; i < n; i += 256){
            int dl = ES[i].y - nbase;
            int p = atomicAdd(&cur[dl], 1);
            csr_src[off0 + sc[dl] + p] = ES[i].x;
        }
        if(!single) __syncthreads();
    }
}

// ---------------- dense GEMM, K-tiled: out[row] = fp16( (A@W)[row] * dinv[row] ) ----------------
// AHALF: A is __half (converted to fp32 in staging). OSTR: output row stride in halfs.
template<bool AHALF, int K, int NC, int KT, int OSTR, bool RELU>
__global__ __launch_bounds__(256) void gemm_k(const void* __restrict__ Araw, const float* __restrict__ W,
                                              const float* __restrict__ dinv,
                                              __half* __restrict__ out, int M){
    constexpr int CHT = KT/4;          // float4 chunks per row per K-tile
    constexpr int CMASK = CHT - 1;
    __shared__ float Xs[64*KT];
    __shared__ float Ws[KT*NC];
    const int tid  = threadIdx.x;
    const int base = blockIdx.x * 64;
    const int tx = tid & 15, ty = tid >> 4;
    const int c0 = tx * 4;
    float acc[4][4] = {};

    for(int k0 = 0; k0 < K; k0 += KT){
        {
            const float4* Wv = (const float4*)(W + k0*NC);
            float4* Wsv = (float4*)Ws;
            for(int i = tid; i < KT*NC/4; i += 256) Wsv[i] = Wv[i];
        }
        {
            const int ch = tid & (CHT - 1);
            const int r0 = tid / CHT;
            constexpr int RSTEP = 256 / CHT;
            #pragma unroll
            for(int r = r0; r < 64; r += RSTEP){
                int row = base + r; if(row >= M) row = M - 1;
                float4 v;
                if(AHALF){
                    const __half2* ap = (const __half2*)((const __half*)Araw + (size_t)row*K + k0 + ch*4);
                    float2 fa = __half22float2(ap[0]), fb = __half22float2(ap[1]);
                    v = make_float4(fa.x, fa.y, fb.x, fb.y);
                } else {
                    v = *(const float4*)((const float*)Araw + (size_t)row*K + k0 + ch*4);
                }
                if(RELU){ v.x=fmaxf(v.x,0.f); v.y=fmaxf(v.y,0.f); v.z=fmaxf(v.z,0.f); v.w=fmaxf(v.w,0.f); }
                int sw = (ch + r) & CMASK;
                *(float4*)&Xs[r*KT + sw*4] = v;
            }
        }
        __syncthreads();

        if(c0 < NC){
            for(int k4 = 0; k4 < CHT; ++k4){
                float4 xs[4];
                #pragma unroll
                for(int i = 0; i < 4; ++i){
                    int r = ty*4 + i;
                    int sw = (k4 + r) & CMASK;
                    xs[i] = *(const float4*)&Xs[r*KT + (sw << 2)];
                }
                float4 wsv[4];
                #pragma unroll
                for(int kk = 0; kk < 4; ++kk) wsv[kk] = *(const float4*)&Ws[(k4*4 + kk)*NC + c0];
                #pragma unroll
                for(int kk = 0; kk < 4; ++kk){
                    const float* wp = (const float*)&wsv[kk];
                    #pragma unroll
                    for(int i = 0; i < 4; ++i){
                        float xv = ((const float*)&xs[i])[kk];
                        #pragma unroll
                        for(int j = 0; j < 4; ++j) acc[i][j] += xv * wp[j];
                    }
                }
            }
        }
        __syncthreads();
    }
    #pragma unroll
    for(int i = 0; i < 4; ++i){
        int row = base + ty*4 + i;
        if(row < M && c0 < NC){
            float dv = dinv[row];
            __half2 h01 = __floats2half2_rn(acc[i][0]*dv, acc[i][1]*dv);
            __half2 h23 = __floats2half2_rn(acc[i][2]*dv, acc[i][3]*dv);
            __half2* dst = (__half2*)&out[(size_t)row*OSTR + c0];
            dst[0] = h01;
            dst[1] = h23;
        }
    }
}

// ---------------- CSR aggregation F=64 -> fp16 G: 16 lanes/edge, 4 edges/wave-instr ----------------
// G[v] = fp16( b + dinv[v]*(sum P[s] + P[v]) ); P fp16 pre-scaled by dinv; fp32 accum.
__global__ __launch_bounds__(256) void agg64_k(const __half* __restrict__ P, const int* __restrict__ rp,
                                               const int* __restrict__ csr_src,
                                               const float* __restrict__ dinv, const float* __restrict__ bias,
                                               __half* __restrict__ G){
    constexpr unsigned F2 = 32;                   // half2 per row
    const int lane = threadIdx.x & 63;
    const int v = (blockIdx.x*256 + threadIdx.x) >> 6;
    if(v >= NN) return;
    const int g = lane >> 4;                      // edge-group 0..3
    const int q = lane & 15;                      // channel-quad
    const unsigned qo = (unsigned)q*2;
    const __half2* __restrict__ P2 = (const __half2*)P;

    const int beg = rp[v], end = rp[v + 1];
    float4 acc = make_float4(0.f, 0.f, 0.f, 0.f);
    if(g == 0){                                   // self-loop term
        __half2 a = P2[(unsigned)v*F2 + qo], b = P2[(unsigned)v*F2 + qo + 1];
        float2 fa = __half22float2(a), fb = __half22float2(b);
        acc = make_float4(fa.x, fa.y, fb.x, fb.y);
    }

    int j = beg;
    #pragma unroll 1
    for(; j + 16 <= end; j += 16){
        unsigned i0 = (unsigned)csr_src[j + g]     *F2 + qo;
        unsigned i1 = (unsigned)csr_src[j + 4 + g] *F2 + qo;
        unsigned i2 = (unsigned)csr_src[j + 8 + g] *F2 + qo;
        unsigned i3 = (unsigned)csr_src[j + 12 + g]*F2 + qo;
        __half2 a0 = P2[i0], b0 = P2[i0+1];
        __half2 a1 = P2[i1], b1 = P2[i1+1];
        __half2 a2 = P2[i2], b2 = P2[i2+1];
        __half2 a3 = P2[i3], b3 = P2[i3+1];
        __half2 sa = __hadd2(a0, a1), sb = __hadd2(b0, b1);
        __half2 ta = __hadd2(a2, a3), tb = __hadd2(b2, b3);
        float2 f0 = __half22float2(sa), f1 = __half22float2(sb);
        float2 f2 = __half22float2(ta), f3 = __half22float2(tb);
        acc.x += f0.x + f2.x; acc.y += f0.y + f2.y;
        acc.z += f1.x + f3.x; acc.w += f1.y + f3.y;
    }
    if(j + 8 <= end){
        unsigned i0 = (unsigned)csr_src[j + g]    *F2 + qo;
        unsigned i1 = (unsigned)csr_src[j + 4 + g]*F2 + qo;
        __half2 a0 = P2[i0], b0 = P2[i0+1];
        __half2 a1 = P2[i1], b1 = P2[i1+1];
        __half2 sa = __hadd2(a0, a1), sb = __hadd2(b0, b1);
        float2 f0 = __half22float2(sa), f1 = __half22float2(sb);
        acc.x += f0.x; acc.y += f0.y; acc.z += f1.x; acc.w += f1.y;
        j += 8;
    }
    if(j + 4 <= end){
        unsigned i0 = (unsigned)csr_src[j + g]*F2 + qo;
        __half2 a = P2[i0], b = P2[i0+1];
        float2 fa = __half22float2(a), fb = __half22float2(b);
        acc.x += fa.x; acc.y += fa.y; acc.z += fb.x; acc.w += fb.y;
        j += 4;
    }
    const int rem = end - j;                      // 0..3
    if(g < rem){
        unsigned i0 = (unsigned)csr_src[j + g]*F2 + qo;
        __half2 a = P2[i0], b = P2[i0+1];
        float2 fa = __half22float2(a), fb = __half22float2(b);
        acc.x += fa.x; acc.y += fa.y; acc.z += fb.x; acc.w += fb.y;
    }

    // reduce across the 4 edge-groups (butterfly over lane bits 4,5)
    #pragma unroll
    for(int m = 16; m <= 32; m <<= 1){
        acc.x += __shfl_xor(acc.x, m, 64);
        acc.y += __shfl_xor(acc.y, m, 64);
        acc.z += __shfl_xor(acc.z, m, 64);
        acc.w += __shfl_xor(acc.w, m, 64);
    }

    if(g == 0){
        const float d = dinv[v];
        float4 bb = *(const float4*)&bias[q*4];
        __half2 h01 = __floats2half2_rn(fmaf(acc.x, d, bb.x), fmaf(acc.y, d, bb.y));
        __half2 h23 = __floats2half2_rn(fmaf(acc.z, d, bb.z), fmaf(acc.w, d, bb.w));
        __half2* dst = (__half2*)&G[(size_t)v*64 + q*4];
        dst[0] = h01;
        dst[1] = h23;
    }
}

// ---------------- final CSR aggregation (F=40, padded stride 64) + fused log_softmax ----------------
__global__ __launch_bounds__(256) void agg40_k(const __half* __restrict__ P, const int* __restrict__ rp,
                                               const int* __restrict__ csr_src,
                                               const float* __restrict__ dinv, const float* __restrict__ bias,
                                               float* __restrict__ G){
    constexpr int NQ = 10;
    constexpr unsigned F2 = 32;                   // padded half2 stride (128B rows)
    const int lane = threadIdx.x & 63;
    const int v = (blockIdx.x*256 + threadIdx.x) >> 6;
    if(v >= NN) return;
    const int g = lane >> 4;                      // edge-group 0..3
    const int q = lane & 15;                      // channel-quad
    const bool qa = (q < NQ);
    const unsigned qo = (unsigned)q*2;
    const __half2* __restrict__ P2 = (const __half2*)P;

    const int beg = rp[v], end = rp[v + 1];
    float4 acc = make_float4(0.f, 0.f, 0.f, 0.f);
    if(g == 0 && qa){
        __half2 a = P2[(unsigned)v*F2 + qo], b = P2[(unsigned)v*F2 + qo + 1];
        float2 fa = __half22float2(a), fb = __half22float2(b);
        acc = make_float4(fa.x, fa.y, fb.x, fb.y);
    }

    int j = beg;
    #pragma unroll 1
    for(; j + 8 <= end; j += 8){
        unsigned i0 = (unsigned)csr_src[j + g]    *F2 + qo;
        unsigned i1 = (unsigned)csr_src[j + 4 + g]*F2 + qo;
        __half2 a0 = P2[i0], b0 = P2[i0+1];
        __half2 a1 = P2[i1], b1 = P2[i1+1];
        __half2 sa = __hadd2(a0, a1), sb = __hadd2(b0, b1);
        float2 f0 = __half22float2(sa), f1 = __half22float2(sb);
        acc.x += f0.x; acc.y += f0.y; acc.z += f1.x; acc.w += f1.y;
    }
    if(j + 4 <= end){
        unsigned i0 = (unsigned)csr_src[j + g]*F2 + qo;
        __half2 a = P2[i0], b = P2[i0+1];
        float2 fa = __half22float2(a), fb = __half22float2(b);
        acc.x += fa.x; acc.y += fa.y; acc.z += fb.x; acc.w += fb.y;
        j += 4;
    }
    const int rem = end - j;                      // 0..3
    if(g < rem){
        unsigned i0 = (unsigned)csr_src[j + g]*F2 + qo;
        __half2 a = P2[i0], b = P2[i0+1];
        float2 fa = __half22float2(a), fb = __half22float2(b);
        acc.x += fa.x; acc.y += fa.y; acc.z += fb.x; acc.w += fb.y;
    }

    #pragma unroll
    for(int m = 16; m <= 32; m <<= 1){
        acc.x += __shfl_xor(acc.x, m, 64);
        acc.y += __shfl_xor(acc.y, m, 64);
        acc.z += __shfl_xor(acc.z, m, 64);
        acc.w += __shfl_xor(acc.w, m, 64);
    }

    float4 r;
    const float d = dinv[v];
    if(g == 0 && qa){
        float4 bb = *(const float4*)&bias[q*4];
        r.x = fmaf(acc.x, d, bb.x);
        r.y = fmaf(acc.y, d, bb.y);
        r.z = fmaf(acc.z, d, bb.z);
        r.w = fmaf(acc.w, d, bb.w);
    }
    // fused log_softmax: butterfly over lane bits 0..3 (within 16-lane group); group 0 authoritative
    float lm = (g == 0 && qa) ? fmaxf(fmaxf(r.x, r.y), fmaxf(r.z, r.w)) : -3.402823466e38f;
    #pragma unroll
    for(int m = 1; m <= 8; m <<= 1) lm = fmaxf(lm, __shfl_xor(lm, m, 64));
    float ls = (g == 0 && qa)
             ? (__expf(r.x - lm) + __expf(r.y - lm) + __expf(r.z - lm) + __expf(r.w - lm)) : 0.0f;
    #pragma unroll
    for(int m = 1; m <= 8; m <<= 1) ls += __shfl_xor(ls, m, 64);
    if(g == 0 && qa){
        float lz = lm + __logf(ls);
        r.x -= lz; r.y -= lz; r.z -= lz; r.w -= lz;
        *(float4*)&G[(size_t)v*40 + q*4] = r;
    }
}

extern "C" void kernel_launch(void* const* d_in, const int* in_sizes, int n_in,
                              void* d_out, int out_size, void* d_ws, size_t ws_size,
                              hipStream_t stream){
    const float* x   = (const float*)d_in[0];
    const int*   e32 = (const int*)  d_in[1];
    const float* W1  = (const float*)d_in[2];
    const float* b1  = (const float*)d_in[3];
    const float* W2  = (const float*)d_in[4];
    const float* b2  = (const float*)d_in[5];
    const float* W3  = (const float*)d_in[6];
    const float* b3  = (const float*)d_in[7];
    float* out = (float*)d_out;

    char* ws = (char*)d_ws;
    size_t off = 0;
    auto alloc = [&](size_t bytes) -> void* {
        void* p = ws + off;
        off = (off + bytes + 255) & ~(size_t)255;
        return p;
    };
    int*    binCur = (int*)   alloc((size_t)NBIN*PAD*4);   // 32KB, zeroed
    int*    rp     = (int*)   alloc((size_t)(NN+1)*4);
    float*  dinv   = (float*) alloc((size_t)NN*4);
    int*    csr_s  = (int*)   alloc((size_t)NE*4);
    __half* ph     = (__half*)alloc((size_t)NN*64*2);   // fp16 message matrix P (stride 64 all layers)
    __half* gA     = (__half*)alloc((size_t)NN*64*2);   // fp16 intermediate G
    __half* gB     = (__half*)alloc((size_t)NN*64*2);
    int2*   bins   = (int2*)  alloc((size_t)NBIN*BCAP*8); // 12.6MB fixed-capacity bins

    hipMemsetAsync(binCur, 0, (size_t)NBIN*PAD*4, stream);
    binC_k<<<(NE + EPB - 1)/EPB, 256, 0, stream>>>(e32, binCur, bins);
    binD_k<<<NBIN, 256, 0, stream>>>(bins, binCur, rp, dinv, csr_s);

    const int GEMM_GRID = (NN + 63)/64;        // 1563
    const int AGG_GRID  = (NN*64 + 255)/256;   // 25000

    gemm_k<false,128,64,64,64,false><<<GEMM_GRID, 256, 0, stream>>>(x,  W1, dinv, ph, NN);
    agg64_k<<<AGG_GRID, 256, 0, stream>>>(ph, rp, csr_s, dinv, b1, gA);
    gemm_k<true, 64,64,64,64,true ><<<GEMM_GRID, 256, 0, stream>>>(gA, W2, dinv, ph, NN);
    agg64_k<<<AGG_GRID, 256, 0, stream>>>(ph, rp, csr_s, dinv, b2, gB);
    gemm_k<true, 64,40,64,64,true ><<<GEMM_GRID, 256, 0, stream>>>(gB, W3, dinv, ph, NN);
    agg40_k<<<AGG_GRID, 256, 0, stream>>>(ph, rp, csr_s, dinv, b3, out);
}